// Round 5
// baseline (869.215 us; speedup 1.0000x reference)
//
#include <hip/hip_runtime.h>
#include <hip/hip_bf16.h>

typedef __attribute__((ext_vector_type(8))) short bf16x8;
typedef __attribute__((ext_vector_type(4))) float f32x4;

#define DEVI static __device__ __forceinline__

constexpr int DM  = 1024;   // d_model
constexpr int NH  = 16;     // heads
constexpr int FFD = 4096;
constexpr int BB  = 8;      // batch
constexpr int SEQ = 1024;
constexpr int TT  = BB * SEQ;  // 8192 tokens

DEVI float bf2f(unsigned short u) {
    union { unsigned u32; float f; } v; v.u32 = ((unsigned)u) << 16; return v.f;
}
DEVI unsigned short f2bf(float f) {
    union { float f; unsigned u; } v; v.f = f;
    unsigned x = v.u;
    return (unsigned short)((x + 0x7fffu + ((x >> 16) & 1u)) >> 16); // RNE
}

DEVI void async_ld16(void* lds, const void* g) {
    __builtin_amdgcn_global_load_lds(
        (const __attribute__((address_space(1))) unsigned int*)g,
        (__attribute__((address_space(3))) unsigned int*)lds, 16, 0, 0);
}

// ---------------------------------------------------------------- mega convert
__global__ __launch_bounds__(256)
void k_cvt_all(const float* __restrict__ s0, unsigned short* __restrict__ d0,   // x    8M
               const float* __restrict__ s1, unsigned short* __restrict__ d1,   // mem  8M
               const float* __restrict__ s2, unsigned short* __restrict__ d2,   // Wq1  1M
               const float* __restrict__ s3, unsigned short* __restrict__ d3,   // Wk1
               const float* __restrict__ s4, unsigned short* __restrict__ d4,   // Wv1
               const float* __restrict__ s5, unsigned short* __restrict__ d5,   // Wq2
               const float* __restrict__ s6, unsigned short* __restrict__ d6,   // Wk2
               const float* __restrict__ s7, unsigned short* __restrict__ d7,   // Wv2
               const float* __restrict__ s8, unsigned short* __restrict__ d8,   // W1   4M
               const float* __restrict__ s9, unsigned short* __restrict__ d9) { // W2   4M
    int b = blockIdx.x;
    const float* s; unsigned short* d;
    if      (b < 8192)  { s = s0; d = d0; }
    else if (b < 16384) { s = s1; d = d1; b -= 8192; }
    else if (b < 17408) { s = s2; d = d2; b -= 16384; }
    else if (b < 18432) { s = s3; d = d3; b -= 17408; }
    else if (b < 19456) { s = s4; d = d4; b -= 18432; }
    else if (b < 20480) { s = s5; d = d5; b -= 19456; }
    else if (b < 21504) { s = s6; d = d6; b -= 20480; }
    else if (b < 22528) { s = s7; d = d7; b -= 21504; }
    else if (b < 26624) { s = s8; d = d8; b -= 22528; }
    else                { s = s9; d = d9; b -= 26624; }
    const int i = (b * 256 + threadIdx.x) * 4;
    float4 v = *reinterpret_cast<const float4*>(s + i);
    ushort4 o;
    o.x = f2bf(v.x); o.y = f2bf(v.y); o.z = f2bf(v.z); o.w = f2bf(v.w);
    *reinterpret_cast<ushort4*>(d + i) = o;
}

// ---------------------------------------------------------------- GEMM
// C[M,N] = act(A[M,K] @ W[N,K]^T + bias). 128x128 tile, BK=32, m97 two-barrier
// K-loop (single buffer — R4 post-mortem: pointer-based dbuf adds an alias-forced
// vmcnt(0) before ds_reads; two-barrier is faster at this occupancy).
// LDS layout per 16-row segment: [kchunk(4)][row(16)] 16B granules, so the b128
// fragment read is bank=(l15*4+j)%32 -> 2-way (free, m136). Verified 0 conflicts (R4).
// SWZ=1: A-strips XCD-exclusive; SWZ=2: W-strips XCD-exclusive.
template <int ACT, int BIAS_ROW, int SWZ>
__global__ __launch_bounds__(256)
void k_gemm(const unsigned short* __restrict__ A,
            const unsigned short* __restrict__ W,
            const float* __restrict__ bias1, const float* __restrict__ bias2,
            unsigned short* __restrict__ C,
            int M, int N, int K, int Nsplit) {
    __shared__ __align__(16) unsigned short As[128 * 32];
    __shared__ __align__(16) unsigned short Bs[128 * 32];
    const int tid  = threadIdx.x;
    const int lane = tid & 63, wave = tid >> 6;
    const int wm = wave & 1, wn = wave >> 1;
    const int l15 = lane & 15, quad = lane >> 4;

    int bx, by;
    if (SWZ == 1) {
        const int id = blockIdx.y * gridDim.x + blockIdx.x;
        const int xcd = id & 7, i2 = id >> 3;
        bx = i2 % gridDim.x;
        by = (i2 / gridDim.x) * 8 + xcd;
    } else if (SWZ == 2) {
        const int id = blockIdx.y * gridDim.x + blockIdx.x;
        const int xcd = id & 7, i2 = id >> 3;
        by = i2 % gridDim.y;
        bx = (i2 / gridDim.y) * 8 + xcd;
    } else { bx = blockIdx.x; by = blockIdx.y; }
    const int m0 = by * 128;
    const int n0 = bx * 128;

    f32x4 acc[4][4];
#pragma unroll
    for (int i = 0; i < 4; i++)
#pragma unroll
        for (int j = 0; j < 4; j++) acc[i][j] = (f32x4){0.f, 0.f, 0.f, 0.f};

    // staging: lane i of wave w fetches row (w*32 + seg*16 + (i&15)), 16B chunk (i>>4)
    const int srow = lane & 15;
    const int scc  = (lane >> 4) * 8;
    const unsigned short* Ag = A + (size_t)(m0 + wave * 32 + srow) * K + scc;
    const unsigned short* Wg = W + (size_t)(n0 + wave * 32 + srow) * K + scc;
    const size_t K16 = (size_t)16 * K;
    const int so = wave * 1024;   // wave's two 512-elem segments

    for (int kb = 0; kb < K; kb += 32) {
        __syncthreads();
        async_ld16(As + so,       Ag + kb);
        async_ld16(As + so + 512, Ag + K16 + kb);
        async_ld16(Bs + so,       Wg + kb);
        async_ld16(Bs + so + 512, Wg + K16 + kb);
        __syncthreads();
        bf16x8 af[4], bfv[4];
#pragma unroll
        for (int mt = 0; mt < 4; mt++)
            af[mt] = *(const bf16x8*)(As + (wm * 4 + mt) * 512 + quad * 128 + l15 * 8);
#pragma unroll
        for (int nt = 0; nt < 4; nt++)
            bfv[nt] = *(const bf16x8*)(Bs + (wn * 4 + nt) * 512 + quad * 128 + l15 * 8);
#pragma unroll
        for (int mt = 0; mt < 4; mt++)
#pragma unroll
            for (int nt = 0; nt < 4; nt++)
                acc[mt][nt] = __builtin_amdgcn_mfma_f32_16x16x32_bf16(af[mt], bfv[nt], acc[mt][nt], 0, 0, 0);
    }

#pragma unroll
    for (int mt = 0; mt < 4; mt++)
#pragma unroll
        for (int nt = 0; nt < 4; nt++) {
            const int col = n0 + wn * 64 + nt * 16 + l15;
            float bcol = 0.f;
            if (!BIAS_ROW) bcol = col < Nsplit ? bias1[col] : bias2[col - Nsplit];
#pragma unroll
            for (int r = 0; r < 4; r++) {
                const int row = m0 + wm * 64 + mt * 16 + quad * 4 + r;
                float v = acc[mt][nt][r] + (BIAS_ROW ? bias1[row] : bcol);
                if (ACT == 1) v = v > 0.f ? v : 0.f;
                C[(size_t)row * N + col] = f2bf(v);
            }
        }
}

// ---------------------------------------------------------------- flash attention (S^T orientation)
__global__ __launch_bounds__(256)
void k_attn(const unsigned short* __restrict__ Q,
            const unsigned short* __restrict__ K,
            const unsigned short* __restrict__ Vt,
            unsigned short* __restrict__ O,
            int qld, int kld) {
    constexpr int LDP = 72;
    __shared__ __align__(16) unsigned short Ks[64 * 64];  // [key][d]   swizzled chunks
    __shared__ __align__(16) unsigned short Vs[64 * 64];  // [d][key]   swizzled chunks
    __shared__ __align__(16) unsigned short Ps[4][32 * LDP];  // per wave: [q][key]
    const int tid  = threadIdx.x;
    const int lane = tid & 63, wave = tid >> 6;
    const int l15 = lane & 15, quad = lane >> 4;
    const int bh = blockIdx.y;
    const int b = bh >> 4, h = bh & 15;
    const int q0 = blockIdx.x * 128 + wave * 32;

    bf16x8 aq[2][2];
#pragma unroll
    for (int ntQ = 0; ntQ < 2; ntQ++)
#pragma unroll
        for (int kc = 0; kc < 2; kc++)
            aq[ntQ][kc] = *(const bf16x8*)(Q + (size_t)(b * SEQ + q0 + ntQ * 16 + l15) * qld
                                             + h * 64 + kc * 32 + quad * 8);

    f32x4 o_[4][2];
#pragma unroll
    for (int i = 0; i < 4; i++)
#pragma unroll
        for (int j = 0; j < 2; j++) o_[i][j] = (f32x4){0.f, 0.f, 0.f, 0.f};
    float m_[2] = {-1e30f, -1e30f}, l_[2] = {0.f, 0.f};

    const int srow  = lane >> 3;                 // 0..7
    const int ctrue = (lane & 7) ^ srow;         // swizzled 16B chunk
    const int seg0 = wave, seg1 = wave + 4;
    const unsigned short* Kg = K  + (size_t)(b * SEQ) * kld + h * 64 + ctrue * 8;
    const unsigned short* Vg = Vt + (size_t)(h * 64) * TT + b * SEQ + ctrue * 8;

    for (int kt = 0; kt < SEQ; kt += 64) {
        __syncthreads();
        async_ld16(Ks + seg0 * 512, Kg + (size_t)(kt + seg0 * 8 + srow) * kld);
        async_ld16(Ks + seg1 * 512, Kg + (size_t)(kt + seg1 * 8 + srow) * kld);
        async_ld16(Vs + seg0 * 512, Vg + (size_t)(seg0 * 8 + srow) * TT + kt);
        async_ld16(Vs + seg1 * 512, Vg + (size_t)(seg1 * 8 + srow) * TT + kt);
        __syncthreads();

        f32x4 s[4][2];
#pragma unroll
        for (int i = 0; i < 4; i++)
#pragma unroll
            for (int j = 0; j < 2; j++) s[i][j] = (f32x4){0.f, 0.f, 0.f, 0.f};
#pragma unroll
        for (int kc = 0; kc < 2; kc++)
#pragma unroll
            for (int mtK = 0; mtK < 4; mtK++) {
                const int pos = (kc * 4 + quad) ^ (l15 & 7);
                bf16x8 kf = *(const bf16x8*)(Ks + (mtK * 16 + l15) * 64 + pos * 8);
#pragma unroll
                for (int ntQ = 0; ntQ < 2; ntQ++)
                    s[mtK][ntQ] = __builtin_amdgcn_mfma_f32_16x16x32_bf16(kf, aq[ntQ][kc], s[mtK][ntQ], 0, 0, 0);
            }

#pragma unroll
        for (int ntQ = 0; ntQ < 2; ntQ++) {
            float mx = -1e30f;
#pragma unroll
            for (int mtK = 0; mtK < 4; mtK++)
#pragma unroll
                for (int r = 0; r < 4; r++) mx = fmaxf(mx, s[mtK][ntQ][r]);
            mx = fmaxf(mx, __shfl_xor(mx, 16));
            mx = fmaxf(mx, __shfl_xor(mx, 32));
            const float mnew  = fmaxf(m_[ntQ], mx * 0.125f);
            const float alpha = __expf(m_[ntQ] - mnew);
            m_[ntQ] = mnew;
            float sum = 0.f;
#pragma unroll
            for (int mtK = 0; mtK < 4; mtK++) {
                float p0 = __expf(fmaf(s[mtK][ntQ][0], 0.125f, -mnew));
                float p1 = __expf(fmaf(s[mtK][ntQ][1], 0.125f, -mnew));
                float p2 = __expf(fmaf(s[mtK][ntQ][2], 0.125f, -mnew));
                float p3 = __expf(fmaf(s[mtK][ntQ][3], 0.125f, -mnew));
                sum += (p0 + p1) + (p2 + p3);
                ushort4 pk;
                pk.x = f2bf(p0); pk.y = f2bf(p1); pk.z = f2bf(p2); pk.w = f2bf(p3);
                *(ushort4*)(&Ps[wave][(ntQ * 16 + l15) * LDP + mtK * 16 + quad * 4]) = pk;
            }
            sum += __shfl_xor(sum, 16);
            sum += __shfl_xor(sum, 32);
            l_[ntQ] = l_[ntQ] * alpha + sum;
#pragma unroll
            for (int mtD = 0; mtD < 4; mtD++)
#pragma unroll
                for (int r = 0; r < 4; r++) o_[mtD][ntQ][r] *= alpha;
        }
        __asm__ volatile("s_waitcnt lgkmcnt(0)" ::: "memory");

        bf16x8 pf[2][2];
#pragma unroll
        for (int ntQ = 0; ntQ < 2; ntQ++)
#pragma unroll
            for (int kc2 = 0; kc2 < 2; kc2++)
                pf[ntQ][kc2] = *(const bf16x8*)(&Ps[wave][(ntQ * 16 + l15) * LDP + kc2 * 32 + quad * 8]);
#pragma unroll
        for (int kc2 = 0; kc2 < 2; kc2++)
#pragma unroll
            for (int mtD = 0; mtD < 4; mtD++) {
                const int pos = (kc2 * 4 + quad) ^ (l15 & 7);
                bf16x8 vf = *(const bf16x8*)(Vs + (mtD * 16 + l15) * 64 + pos * 8);
#pragma unroll
                for (int ntQ = 0; ntQ < 2; ntQ++)
                    o_[mtD][ntQ] = __builtin_amdgcn_mfma_f32_16x16x32_bf16(vf, pf[ntQ][kc2], o_[mtD][ntQ], 0, 0, 0);
            }
    }

#pragma unroll
    for (int ntQ = 0; ntQ < 2; ntQ++) {
        const float rl = 1.f / l_[ntQ];
        const size_t tok = (size_t)b * SEQ + q0 + ntQ * 16 + l15;
#pragma unroll
        for (int mtD = 0; mtD < 4; mtD++) {
            ushort4 ov;
            ov.x = f2bf(o_[mtD][ntQ][0] * rl);
            ov.y = f2bf(o_[mtD][ntQ][1] * rl);
            ov.z = f2bf(o_[mtD][ntQ][2] * rl);
            ov.w = f2bf(o_[mtD][ntQ][3] * rl);
            *(ushort4*)(O + tok * DM + h * 64 + mtD * 16 + quad * 4) = ov;
        }
    }
}

// ---------------------------------------------------------------- fused add + LayerNorm
__global__ __launch_bounds__(256)
void k_add_ln(const unsigned short* __restrict__ Xa,
              const unsigned short* __restrict__ Xb,
              const float* __restrict__ g, const float* __restrict__ be,
              unsigned short* __restrict__ Y, float* __restrict__ Yf) {
    const int row = blockIdx.x;
    const int base = threadIdx.x * 4;
    const size_t off = (size_t)row * DM + base;
    ushort4 xa = *(const ushort4*)(Xa + off);
    ushort4 xb = *(const ushort4*)(Xb + off);
    float v[4];
    v[0] = bf2f(xa.x) + bf2f(xb.x);
    v[1] = bf2f(xa.y) + bf2f(xb.y);
    v[2] = bf2f(xa.z) + bf2f(xb.z);
    v[3] = bf2f(xa.w) + bf2f(xb.w);
    float s1 = v[0] + v[1] + v[2] + v[3];
    float s2 = v[0]*v[0] + v[1]*v[1] + v[2]*v[2] + v[3]*v[3];
#pragma unroll
    for (int o = 32; o; o >>= 1) { s1 += __shfl_xor(s1, o); s2 += __shfl_xor(s2, o); }
    __shared__ float rs1[4], rs2[4];
    if ((threadIdx.x & 63) == 0) { rs1[threadIdx.x >> 6] = s1; rs2[threadIdx.x >> 6] = s2; }
    __syncthreads();
    s1 = rs1[0] + rs1[1] + rs1[2] + rs1[3];
    s2 = rs2[0] + rs2[1] + rs2[2] + rs2[3];
    const float mu = s1 * (1.f / DM);
    const float var = s2 * (1.f / DM) - mu * mu;
    const float rstd = rsqrtf(var + 1e-5f);
    float y[4];
#pragma unroll
    for (int j = 0; j < 4; j++) y[j] = (v[j] - mu) * rstd * g[base + j] + be[base + j];
    if (Y) {
        ushort4 o;
        o.x = f2bf(y[0]); o.y = f2bf(y[1]); o.z = f2bf(y[2]); o.w = f2bf(y[3]);
        *(ushort4*)(Y + off) = o;
    }
    if (Yf) *(float4*)(Yf + off) = (float4){y[0], y[1], y[2], y[3]};
}

// ---------------------------------------------------------------- launch
extern "C" void kernel_launch(void* const* d_in, const int* in_sizes, int n_in,
                              void* d_out, int out_size, void* d_ws, size_t ws_size,
                              hipStream_t stream) {
    const float* x    = (const float*)d_in[0];
    const float* mem  = (const float*)d_in[1];
    const float* Wq1  = (const float*)d_in[2];  const float* bq1 = (const float*)d_in[3];
    const float* Wk1  = (const float*)d_in[4];  const float* bk1 = (const float*)d_in[5];
    const float* Wv1  = (const float*)d_in[6];  const float* bv1 = (const float*)d_in[7];
    const float* Wq2  = (const float*)d_in[8];  const float* bq2 = (const float*)d_in[9];
    const float* Wk2  = (const float*)d_in[10]; const float* bk2 = (const float*)d_in[11];
    const float* Wv2  = (const float*)d_in[12]; const float* bv2 = (const float*)d_in[13];
    const float* W1   = (const float*)d_in[14]; const float* b1  = (const float*)d_in[15];
    const float* W2   = (const float*)d_in[16]; const float* b2  = (const float*)d_in[17];
    const float* g1   = (const float*)d_in[18]; const float* be1 = (const float*)d_in[19];
    const float* g2   = (const float*)d_in[20]; const float* be2 = (const float*)d_in[21];
    const float* g3   = (const float*)d_in[22]; const float* be3 = (const float*)d_in[23];
    float* out = (float*)d_out;

    const size_t MiB = 1u << 20;
    char* w = (char*)d_ws;
    unsigned short* Wq1b = (unsigned short*)(w + 0 * MiB);   // Wq1b/Wk1b adjacent => QK concat
    unsigned short* Wk1b = (unsigned short*)(w + 2 * MiB);
    unsigned short* Wv1b = (unsigned short*)(w + 4 * MiB);
    unsigned short* Wq2b = (unsigned short*)(w + 6 * MiB);
    unsigned short* Wk2b = (unsigned short*)(w + 8 * MiB);
    unsigned short* Wv2b = (unsigned short*)(w + 10 * MiB);
    unsigned short* W1b  = (unsigned short*)(w + 12 * MiB);
    unsigned short* W2b  = (unsigned short*)(w + 20 * MiB);
    unsigned short* xb   = (unsigned short*)(w + 28 * MiB);
    unsigned short* mb   = (unsigned short*)(w + 44 * MiB);
    unsigned short* QKb  = (unsigned short*)(w + 60 * MiB);  // self: [TT,2048] (32 MiB)
    unsigned short* Qb2  = (unsigned short*)(w + 60 * MiB);  // cross: [TT,1024]
    unsigned short* Kb2  = (unsigned short*)(w + 76 * MiB);  // cross: [TT,1024]
    unsigned short* Vtb  = (unsigned short*)(w + 92 * MiB);  // [DM][TT]
    unsigned short* Ab   = (unsigned short*)(w + 108 * MiB);
    unsigned short* x1b  = (unsigned short*)(w + 124 * MiB);
    unsigned short* x2b  = (unsigned short*)(w + 140 * MiB);
    unsigned short* h1b  = (unsigned short*)(w + 60 * MiB);   // 64 MiB, overlays QK/Vt/Ab (dead)
    unsigned short* h2b  = (unsigned short*)(w + 124 * MiB);  // overlays x1 (dead)

    const dim3 blk(256);
    k_cvt_all<<<30720, blk, 0, stream>>>(x, xb, mem, mb, Wq1, Wq1b, Wk1, Wk1b,
                                         Wv1, Wv1b, Wq2, Wq2b, Wk2, Wk2b,
                                         Wv2, Wv2b, W1, W1b, W2, W2b);

    const dim3 gD(DM / 128, TT / 128);     // N=1024
    const dim3 gQK(2048 / 128, TT / 128);  // N=2048 fused QK
    const dim3 gVt(TT / 128, DM / 128);    // C [DM, TT]
    const dim3 gF(FFD / 128, TT / 128);
    const dim3 gA(SEQ / 128, BB * NH);

    // self-attention
    k_gemm<0,0,1><<<gQK, blk, 0, stream>>>(xb,   Wq1b, bq1, bk1, QKb, TT, 2048, DM, 1024);
    k_gemm<0,1,2><<<gVt, blk, 0, stream>>>(Wv1b, xb,   bv1, bv1, Vtb, DM, TT, DM, TT);
    k_attn<<<gA, blk, 0, stream>>>(QKb, QKb + 1024, Vtb, Ab, 2048, 2048);
    k_add_ln<<<TT, blk, 0, stream>>>(xb, Ab, g1, be1, x1b, nullptr);
    // cross-attention
    k_gemm<0,0,1><<<gD,  blk, 0, stream>>>(x1b,  Wq2b, bq2, bq2, Qb2, TT, DM, DM, DM);
    k_gemm<0,0,1><<<gD,  blk, 0, stream>>>(mb,   Wk2b, bk2, bk2, Kb2, TT, DM, DM, DM);
    k_gemm<0,1,2><<<gVt, blk, 0, stream>>>(Wv2b, mb,   bv2, bv2, Vtb, DM, TT, DM, TT);
    k_attn<<<gA, blk, 0, stream>>>(Qb2, Kb2, Vtb, Ab, 1024, 1024);
    k_add_ln<<<TT, blk, 0, stream>>>(x1b, Ab, g2, be2, x2b, nullptr);
    // FFN
    k_gemm<1,0,0><<<gF, blk, 0, stream>>>(x2b, W1b, b1, b1, h1b, TT, FFD, DM, FFD);
    k_gemm<0,0,1><<<gD, blk, 0, stream>>>(h1b, W2b, b2, b2, h2b, TT, DM, FFD, DM);
    k_add_ln<<<TT, blk, 0, stream>>>(x2b, h2b, g3, be3, nullptr, out);
}

// Round 6
// 743.076 us; speedup vs baseline: 1.1698x; 1.1698x over previous
//
#include <hip/hip_runtime.h>
#include <hip/hip_bf16.h>

typedef __attribute__((ext_vector_type(8))) short bf16x8;
typedef __attribute__((ext_vector_type(4))) float f32x4;

#define DEVI static __device__ __forceinline__

constexpr int DM  = 1024;   // d_model
constexpr int NH  = 16;     // heads
constexpr int FFD = 4096;
constexpr int BB  = 8;      // batch
constexpr int SEQ = 1024;
constexpr int TT  = BB * SEQ;  // 8192 tokens

DEVI float bf2f(unsigned short u) {
    union { unsigned u32; float f; } v; v.u32 = ((unsigned)u) << 16; return v.f;
}
DEVI unsigned short f2bf(float f) {
    union { float f; unsigned u; } v; v.f = f;
    unsigned x = v.u;
    return (unsigned short)((x + 0x7fffu + ((x >> 16) & 1u)) >> 16); // RNE
}

DEVI void async_ld16(void* lds, const void* g) {
    __builtin_amdgcn_global_load_lds(
        (const __attribute__((address_space(1))) unsigned int*)g,
        (__attribute__((address_space(3))) unsigned int*)lds, 16, 0, 0);
}

// ---------------------------------------------------------------- mega convert
__global__ __launch_bounds__(256)
void k_cvt_all(const float* __restrict__ s0, unsigned short* __restrict__ d0,   // x    8M
               const float* __restrict__ s1, unsigned short* __restrict__ d1,   // mem  8M
               const float* __restrict__ s2, unsigned short* __restrict__ d2,   // Wq1  1M
               const float* __restrict__ s3, unsigned short* __restrict__ d3,   // Wk1
               const float* __restrict__ s4, unsigned short* __restrict__ d4,   // Wv1
               const float* __restrict__ s5, unsigned short* __restrict__ d5,   // Wq2
               const float* __restrict__ s6, unsigned short* __restrict__ d6,   // Wk2
               const float* __restrict__ s7, unsigned short* __restrict__ d7,   // Wv2
               const float* __restrict__ s8, unsigned short* __restrict__ d8,   // W1   4M
               const float* __restrict__ s9, unsigned short* __restrict__ d9) { // W2   4M
    int b = blockIdx.x;
    const float* s; unsigned short* d;
    if      (b < 8192)  { s = s0; d = d0; }
    else if (b < 16384) { s = s1; d = d1; b -= 8192; }
    else if (b < 17408) { s = s2; d = d2; b -= 16384; }
    else if (b < 18432) { s = s3; d = d3; b -= 17408; }
    else if (b < 19456) { s = s4; d = d4; b -= 18432; }
    else if (b < 20480) { s = s5; d = d5; b -= 19456; }
    else if (b < 21504) { s = s6; d = d6; b -= 20480; }
    else if (b < 22528) { s = s7; d = d7; b -= 21504; }
    else if (b < 26624) { s = s8; d = d8; b -= 22528; }
    else                { s = s9; d = d9; b -= 26624; }
    const int i = (b * 256 + threadIdx.x) * 4;
    float4 v = *reinterpret_cast<const float4*>(s + i);
    ushort4 o;
    o.x = f2bf(v.x); o.y = f2bf(v.y); o.z = f2bf(v.z); o.w = f2bf(v.w);
    *reinterpret_cast<ushort4*>(d + i) = o;
}

// ---------------------------------------------------------------- GEMM (R3 configuration)
// C[M,N] = act(A[M,K] @ W[N,K]^T + bias). 128x128 tile, BK=32, m97 two-barrier
// K-loop. LDS row-major [128][32]; staging lane i -> row i>>2, chunk i&3 so
// consecutive lanes are address-adjacent (64B bursts). R4/R5 post-mortem: the
// [kchunk][row] remap gave 0 LDS conflicts but scattered lane addresses 2KiB
// apart -> 64x16B VMEM requests per instr -> +35% on every GEMM. The 8.4e6
// ds_read conflicts of this layout are overlapped with MFMA (m98) — keep them.
// SWZ=1: A-strips XCD-exclusive; SWZ=2: W-strips XCD-exclusive.
// DUAL=1: grid.y doubled; tiles with by>=gridY/2 use the second operand set.
template <int ACT, int BIAS_ROW, int SWZ, int DUAL>
__global__ __launch_bounds__(256)
void k_gemm(const unsigned short* __restrict__ A,
            const unsigned short* __restrict__ W,
            const float* __restrict__ bias1, const float* __restrict__ bias2,
            unsigned short* __restrict__ C,
            int M, int N, int K, int Nsplit,
            const unsigned short* __restrict__ A2 = nullptr,
            const unsigned short* __restrict__ W2 = nullptr,
            const float* __restrict__ bias1b = nullptr,
            unsigned short* __restrict__ C2 = nullptr) {
    __shared__ __align__(16) unsigned short As[128 * 32];
    __shared__ __align__(16) unsigned short Bs[128 * 32];
    const int tid  = threadIdx.x;
    const int lane = tid & 63, wave = tid >> 6;
    const int wm = wave & 1, wn = wave >> 1;
    const int l15 = lane & 15, quad = lane >> 4;

    int bx, by;
    if (SWZ == 1) {
        const int id = blockIdx.y * gridDim.x + blockIdx.x;
        const int xcd = id & 7, i2 = id >> 3;
        bx = i2 % gridDim.x;
        by = (i2 / gridDim.x) * 8 + xcd;
    } else if (SWZ == 2) {
        const int id = blockIdx.y * gridDim.x + blockIdx.x;
        const int xcd = id & 7, i2 = id >> 3;
        by = i2 % gridDim.y;
        bx = (i2 / gridDim.y) * 8 + xcd;
    } else { bx = blockIdx.x; by = blockIdx.y; }

    const unsigned short* Ap = A;
    const unsigned short* Wp = W;
    const float* b1p = bias1;
    unsigned short* Cp = C;
    if (DUAL) {
        const int half = gridDim.y >> 1;
        if (by >= half) { by -= half; Ap = A2; Wp = W2; b1p = bias1b; Cp = C2; }
    }
    const int m0 = by * 128;
    const int n0 = bx * 128;

    f32x4 acc[4][4];
#pragma unroll
    for (int i = 0; i < 4; i++)
#pragma unroll
        for (int j = 0; j < 4; j++) acc[i][j] = (f32x4){0.f, 0.f, 0.f, 0.f};

    // staging: lane i of wave w fetches row (w*32 + seg*16 + (i>>2)), 16B chunk (i&3)
    const int srow = lane >> 2;          // 0..15
    const int scol = (lane & 3) * 8;     // 0,8,16,24
    const unsigned short* Ag = Ap + (size_t)(m0 + wave * 32 + srow) * K + scol;
    const unsigned short* Wg = Wp + (size_t)(n0 + wave * 32 + srow) * K + scol;
    unsigned short* Al0 = As + (wave * 32) * 32;
    unsigned short* Al1 = As + (wave * 32 + 16) * 32;
    unsigned short* Bl0 = Bs + (wave * 32) * 32;
    unsigned short* Bl1 = Bs + (wave * 32 + 16) * 32;
    const size_t K16 = (size_t)16 * K;

    for (int kb = 0; kb < K; kb += 32) {
        __syncthreads();
        async_ld16(Al0, Ag + kb);
        async_ld16(Al1, Ag + K16 + kb);
        async_ld16(Bl0, Wg + kb);
        async_ld16(Bl1, Wg + K16 + kb);
        __syncthreads();
        bf16x8 af[4], bfv[4];
#pragma unroll
        for (int mt = 0; mt < 4; mt++)
            af[mt] = *(const bf16x8*)(As + (wm * 64 + mt * 16 + l15) * 32 + quad * 8);
#pragma unroll
        for (int nt = 0; nt < 4; nt++)
            bfv[nt] = *(const bf16x8*)(Bs + (wn * 64 + nt * 16 + l15) * 32 + quad * 8);
#pragma unroll
        for (int mt = 0; mt < 4; mt++)
#pragma unroll
            for (int nt = 0; nt < 4; nt++)
                acc[mt][nt] = __builtin_amdgcn_mfma_f32_16x16x32_bf16(af[mt], bfv[nt], acc[mt][nt], 0, 0, 0);
    }

#pragma unroll
    for (int mt = 0; mt < 4; mt++)
#pragma unroll
        for (int nt = 0; nt < 4; nt++) {
            const int col = n0 + wn * 64 + nt * 16 + l15;
            float bcol = 0.f;
            if (!BIAS_ROW) bcol = col < Nsplit ? b1p[col] : bias2[col - Nsplit];
#pragma unroll
            for (int r = 0; r < 4; r++) {
                const int row = m0 + wm * 64 + mt * 16 + quad * 4 + r;
                float v = acc[mt][nt][r] + (BIAS_ROW ? b1p[row] : bcol);
                if (ACT == 1) v = v > 0.f ? v : 0.f;
                Cp[(size_t)row * N + col] = f2bf(v);
            }
        }
}

// ---------------------------------------------------------------- flash attention (S^T orientation)
__global__ __launch_bounds__(256)
void k_attn(const unsigned short* __restrict__ Q,
            const unsigned short* __restrict__ K,
            const unsigned short* __restrict__ Vt,
            unsigned short* __restrict__ O,
            int qld, int kld) {
    constexpr int LDP = 72;
    __shared__ __align__(16) unsigned short Ks[64 * 64];  // [key][d]   swizzled chunks
    __shared__ __align__(16) unsigned short Vs[64 * 64];  // [d][key]   swizzled chunks
    __shared__ __align__(16) unsigned short Ps[4][32 * LDP];  // per wave: [q][key]
    const int tid  = threadIdx.x;
    const int lane = tid & 63, wave = tid >> 6;
    const int l15 = lane & 15, quad = lane >> 4;
    const int bh = blockIdx.y;
    const int b = bh >> 4, h = bh & 15;
    const int q0 = blockIdx.x * 128 + wave * 32;

    bf16x8 aq[2][2];
#pragma unroll
    for (int ntQ = 0; ntQ < 2; ntQ++)
#pragma unroll
        for (int kc = 0; kc < 2; kc++)
            aq[ntQ][kc] = *(const bf16x8*)(Q + (size_t)(b * SEQ + q0 + ntQ * 16 + l15) * qld
                                             + h * 64 + kc * 32 + quad * 8);

    f32x4 o_[4][2];
#pragma unroll
    for (int i = 0; i < 4; i++)
#pragma unroll
        for (int j = 0; j < 2; j++) o_[i][j] = (f32x4){0.f, 0.f, 0.f, 0.f};
    float m_[2] = {-1e30f, -1e30f}, l_[2] = {0.f, 0.f};

    const int srow  = lane >> 3;                 // 0..7
    const int ctrue = (lane & 7) ^ srow;         // swizzled 16B chunk
    const int seg0 = wave, seg1 = wave + 4;
    const unsigned short* Kg = K  + (size_t)(b * SEQ) * kld + h * 64 + ctrue * 8;
    const unsigned short* Vg = Vt + (size_t)(h * 64) * TT + b * SEQ + ctrue * 8;

    for (int kt = 0; kt < SEQ; kt += 64) {
        __syncthreads();
        async_ld16(Ks + seg0 * 512, Kg + (size_t)(kt + seg0 * 8 + srow) * kld);
        async_ld16(Ks + seg1 * 512, Kg + (size_t)(kt + seg1 * 8 + srow) * kld);
        async_ld16(Vs + seg0 * 512, Vg + (size_t)(seg0 * 8 + srow) * TT + kt);
        async_ld16(Vs + seg1 * 512, Vg + (size_t)(seg1 * 8 + srow) * TT + kt);
        __syncthreads();

        f32x4 s[4][2];
#pragma unroll
        for (int i = 0; i < 4; i++)
#pragma unroll
            for (int j = 0; j < 2; j++) s[i][j] = (f32x4){0.f, 0.f, 0.f, 0.f};
#pragma unroll
        for (int kc = 0; kc < 2; kc++)
#pragma unroll
            for (int mtK = 0; mtK < 4; mtK++) {
                const int pos = (kc * 4 + quad) ^ (l15 & 7);
                bf16x8 kf = *(const bf16x8*)(Ks + (mtK * 16 + l15) * 64 + pos * 8);
#pragma unroll
                for (int ntQ = 0; ntQ < 2; ntQ++)
                    s[mtK][ntQ] = __builtin_amdgcn_mfma_f32_16x16x32_bf16(kf, aq[ntQ][kc], s[mtK][ntQ], 0, 0, 0);
            }

#pragma unroll
        for (int ntQ = 0; ntQ < 2; ntQ++) {
            float mx = -1e30f;
#pragma unroll
            for (int mtK = 0; mtK < 4; mtK++)
#pragma unroll
                for (int r = 0; r < 4; r++) mx = fmaxf(mx, s[mtK][ntQ][r]);
            mx = fmaxf(mx, __shfl_xor(mx, 16));
            mx = fmaxf(mx, __shfl_xor(mx, 32));
            const float mnew  = fmaxf(m_[ntQ], mx * 0.125f);
            const float alpha = __expf(m_[ntQ] - mnew);
            m_[ntQ] = mnew;
            float sum = 0.f;
#pragma unroll
            for (int mtK = 0; mtK < 4; mtK++) {
                float p0 = __expf(fmaf(s[mtK][ntQ][0], 0.125f, -mnew));
                float p1 = __expf(fmaf(s[mtK][ntQ][1], 0.125f, -mnew));
                float p2 = __expf(fmaf(s[mtK][ntQ][2], 0.125f, -mnew));
                float p3 = __expf(fmaf(s[mtK][ntQ][3], 0.125f, -mnew));
                sum += (p0 + p1) + (p2 + p3);
                ushort4 pk;
                pk.x = f2bf(p0); pk.y = f2bf(p1); pk.z = f2bf(p2); pk.w = f2bf(p3);
                *(ushort4*)(&Ps[wave][(ntQ * 16 + l15) * LDP + mtK * 16 + quad * 4]) = pk;
            }
            sum += __shfl_xor(sum, 16);
            sum += __shfl_xor(sum, 32);
            l_[ntQ] = l_[ntQ] * alpha + sum;
#pragma unroll
            for (int mtD = 0; mtD < 4; mtD++)
#pragma unroll
                for (int r = 0; r < 4; r++) o_[mtD][ntQ][r] *= alpha;
        }
        __asm__ volatile("s_waitcnt lgkmcnt(0)" ::: "memory");

        bf16x8 pf[2][2];
#pragma unroll
        for (int ntQ = 0; ntQ < 2; ntQ++)
#pragma unroll
            for (int kc2 = 0; kc2 < 2; kc2++)
                pf[ntQ][kc2] = *(const bf16x8*)(&Ps[wave][(ntQ * 16 + l15) * LDP + kc2 * 32 + quad * 8]);
#pragma unroll
        for (int kc2 = 0; kc2 < 2; kc2++)
#pragma unroll
            for (int mtD = 0; mtD < 4; mtD++) {
                const int pos = (kc2 * 4 + quad) ^ (l15 & 7);
                bf16x8 vf = *(const bf16x8*)(Vs + (mtD * 16 + l15) * 64 + pos * 8);
#pragma unroll
                for (int ntQ = 0; ntQ < 2; ntQ++)
                    o_[mtD][ntQ] = __builtin_amdgcn_mfma_f32_16x16x32_bf16(vf, pf[ntQ][kc2], o_[mtD][ntQ], 0, 0, 0);
            }
    }

#pragma unroll
    for (int ntQ = 0; ntQ < 2; ntQ++) {
        const float rl = 1.f / l_[ntQ];
        const size_t tok = (size_t)b * SEQ + q0 + ntQ * 16 + l15;
#pragma unroll
        for (int mtD = 0; mtD < 4; mtD++) {
            ushort4 ov;
            ov.x = f2bf(o_[mtD][ntQ][0] * rl);
            ov.y = f2bf(o_[mtD][ntQ][1] * rl);
            ov.z = f2bf(o_[mtD][ntQ][2] * rl);
            ov.w = f2bf(o_[mtD][ntQ][3] * rl);
            *(ushort4*)(O + tok * DM + h * 64 + mtD * 16 + quad * 4) = ov;
        }
    }
}

// ---------------------------------------------------------------- fused add + LayerNorm
__global__ __launch_bounds__(256)
void k_add_ln(const unsigned short* __restrict__ Xa,
              const unsigned short* __restrict__ Xb,
              const float* __restrict__ g, const float* __restrict__ be,
              unsigned short* __restrict__ Y, float* __restrict__ Yf) {
    const int row = blockIdx.x;
    const int base = threadIdx.x * 4;
    const size_t off = (size_t)row * DM + base;
    ushort4 xa = *(const ushort4*)(Xa + off);
    ushort4 xb = *(const ushort4*)(Xb + off);
    float v[4];
    v[0] = bf2f(xa.x) + bf2f(xb.x);
    v[1] = bf2f(xa.y) + bf2f(xb.y);
    v[2] = bf2f(xa.z) + bf2f(xb.z);
    v[3] = bf2f(xa.w) + bf2f(xb.w);
    float s1 = v[0] + v[1] + v[2] + v[3];
    float s2 = v[0]*v[0] + v[1]*v[1] + v[2]*v[2] + v[3]*v[3];
#pragma unroll
    for (int o = 32; o; o >>= 1) { s1 += __shfl_xor(s1, o); s2 += __shfl_xor(s2, o); }
    __shared__ float rs1[4], rs2[4];
    if ((threadIdx.x & 63) == 0) { rs1[threadIdx.x >> 6] = s1; rs2[threadIdx.x >> 6] = s2; }
    __syncthreads();
    s1 = rs1[0] + rs1[1] + rs1[2] + rs1[3];
    s2 = rs2[0] + rs2[1] + rs2[2] + rs2[3];
    const float mu = s1 * (1.f / DM);
    const float var = s2 * (1.f / DM) - mu * mu;
    const float rstd = rsqrtf(var + 1e-5f);
    float y[4];
#pragma unroll
    for (int j = 0; j < 4; j++) y[j] = (v[j] - mu) * rstd * g[base + j] + be[base + j];
    if (Y) {
        ushort4 o;
        o.x = f2bf(y[0]); o.y = f2bf(y[1]); o.z = f2bf(y[2]); o.w = f2bf(y[3]);
        *(ushort4*)(Y + off) = o;
    }
    if (Yf) *(float4*)(Yf + off) = (float4){y[0], y[1], y[2], y[3]};
}

// ---------------------------------------------------------------- launch
extern "C" void kernel_launch(void* const* d_in, const int* in_sizes, int n_in,
                              void* d_out, int out_size, void* d_ws, size_t ws_size,
                              hipStream_t stream) {
    const float* x    = (const float*)d_in[0];
    const float* mem  = (const float*)d_in[1];
    const float* Wq1  = (const float*)d_in[2];  const float* bq1 = (const float*)d_in[3];
    const float* Wk1  = (const float*)d_in[4];  const float* bk1 = (const float*)d_in[5];
    const float* Wv1  = (const float*)d_in[6];  const float* bv1 = (const float*)d_in[7];
    const float* Wq2  = (const float*)d_in[8];  const float* bq2 = (const float*)d_in[9];
    const float* Wk2  = (const float*)d_in[10]; const float* bk2 = (const float*)d_in[11];
    const float* Wv2  = (const float*)d_in[12]; const float* bv2 = (const float*)d_in[13];
    const float* W1   = (const float*)d_in[14]; const float* b1  = (const float*)d_in[15];
    const float* W2   = (const float*)d_in[16]; const float* b2  = (const float*)d_in[17];
    const float* g1   = (const float*)d_in[18]; const float* be1 = (const float*)d_in[19];
    const float* g2   = (const float*)d_in[20]; const float* be2 = (const float*)d_in[21];
    const float* g3   = (const float*)d_in[22]; const float* be3 = (const float*)d_in[23];
    float* out = (float*)d_out;

    const size_t MiB = 1u << 20;
    char* w = (char*)d_ws;
    unsigned short* Wq1b = (unsigned short*)(w + 0 * MiB);   // Wq1b/Wk1b adjacent => QK concat
    unsigned short* Wk1b = (unsigned short*)(w + 2 * MiB);
    unsigned short* Wv1b = (unsigned short*)(w + 4 * MiB);
    unsigned short* Wq2b = (unsigned short*)(w + 6 * MiB);
    unsigned short* Wk2b = (unsigned short*)(w + 8 * MiB);
    unsigned short* Wv2b = (unsigned short*)(w + 10 * MiB);
    unsigned short* W1b  = (unsigned short*)(w + 12 * MiB);
    unsigned short* W2b  = (unsigned short*)(w + 20 * MiB);
    unsigned short* xb   = (unsigned short*)(w + 28 * MiB);
    unsigned short* mb   = (unsigned short*)(w + 44 * MiB);
    unsigned short* QKb  = (unsigned short*)(w + 60 * MiB);  // self: [TT,2048] (32 MiB)
    unsigned short* Qb2  = (unsigned short*)(w + 60 * MiB);  // cross: [TT,1024]
    unsigned short* Kb2  = (unsigned short*)(w + 76 * MiB);  // cross: [TT,1024]
    unsigned short* Vtb  = (unsigned short*)(w + 92 * MiB);  // [DM][TT]
    unsigned short* Ab   = (unsigned short*)(w + 108 * MiB);
    unsigned short* x1b  = (unsigned short*)(w + 124 * MiB);
    unsigned short* x2b  = (unsigned short*)(w + 140 * MiB);
    unsigned short* h1b  = (unsigned short*)(w + 60 * MiB);   // 64 MiB, overlays QK/Vt/Ab (dead)
    unsigned short* h2b  = (unsigned short*)(w + 124 * MiB);  // overlays x1 (dead)

    const dim3 blk(256);
    k_cvt_all<<<30720, blk, 0, stream>>>(x, xb, mem, mb, Wq1, Wq1b, Wk1, Wk1b,
                                         Wv1, Wv1b, Wq2, Wq2b, Wk2, Wk2b,
                                         Wv2, Wv2b, W1, W1b, W2, W2b);

    const dim3 gD(DM / 128, TT / 128);     // N=1024
    const dim3 gQK(2048 / 128, TT / 128);  // N=2048 fused self QK
    const dim3 gD2(DM / 128, 2 * TT / 128); // dual cross Q+K
    const dim3 gVt(TT / 128, DM / 128);    // C [DM, TT]
    const dim3 gF(FFD / 128, TT / 128);
    const dim3 gA(SEQ / 128, BB * NH);

    // self-attention
    k_gemm<0,0,1,0><<<gQK, blk, 0, stream>>>(xb,   Wq1b, bq1, bk1, QKb, TT, 2048, DM, 1024);
    k_gemm<0,1,2,0><<<gVt, blk, 0, stream>>>(Wv1b, xb,   bv1, bv1, Vtb, DM, TT, DM, TT);
    k_attn<<<gA, blk, 0, stream>>>(QKb, QKb + 1024, Vtb, Ab, 2048, 2048);
    k_add_ln<<<TT, blk, 0, stream>>>(xb, Ab, g1, be1, x1b, nullptr);
    // cross-attention: Q2 (A=x1b) and K2 (A=mem) fused into one dual launch
    k_gemm<0,0,1,1><<<gD2, blk, 0, stream>>>(x1b, Wq2b, bq2, bq2, Qb2, TT, DM, DM, DM,
                                             mb,  Wk2b, bk2, Kb2);
    k_gemm<0,1,2,0><<<gVt, blk, 0, stream>>>(Wv2b, mb,   bv2, bv2, Vtb, DM, TT, DM, TT);
    k_attn<<<gA, blk, 0, stream>>>(Qb2, Kb2, Vtb, Ab, 1024, 1024);
    k_add_ln<<<TT, blk, 0, stream>>>(x1b, Ab, g2, be2, x2b, nullptr);
    // FFN
    k_gemm<1,0,0,0><<<gF, blk, 0, stream>>>(x2b, W1b, b1, b1, h1b, TT, FFD, DM, FFD);
    k_gemm<0,0,1,0><<<gD, blk, 0, stream>>>(h1b, W2b, b2, b2, h2b, TT, DM, FFD, DM);
    k_add_ln<<<TT, blk, 0, stream>>>(x2b, h2b, g3, be3, nullptr, out);
}